// Round 3
// baseline (30.154 us; speedup 1.0000x reference)
//
#include <hip/hip_runtime.h>
#include <math.h>

// ---------------------------------------------------------------------------
// ANI NNP fused: AEV (radial+angular) + 4-layer MLP per atom, block-local sum.
// B=32, A=32, NSPEC=8, AEV=1280 (+approx -> 1281)
// Kernel 1: 256 blocks x 256 threads, block = (batch, 4 atoms) -> partial[256]
// Kernel 2: 1 block, sums 8 partials per batch -> out[32]
// No memset, no global atomics, no workspace round-trip of AEV.
// ---------------------------------------------------------------------------

#define NB 32
#define NA 32

__device__ __forceinline__ float celu01(float x) {
    return x > 0.0f ? x : 0.1f * expm1f(x * 10.0f);
}

__global__ __launch_bounds__(256)
void fused_kernel(const int* __restrict__ species, const float* __restrict__ coords,
                  const int* __restrict__ belong, const float* __restrict__ approx,
                  const float* __restrict__ W1, const float* __restrict__ b1,
                  const float* __restrict__ W2, const float* __restrict__ b2,
                  const float* __restrict__ W3, const float* __restrict__ b3,
                  const float* __restrict__ W4, const float* __restrict__ b4,
                  float* __restrict__ partial) {
    const int blk = blockIdx.x;
    const int b = blk >> 3, grp = blk & 7;     // 4 atoms: ia = grp*4 + li
    const int t = threadIdx.x;
    const float PI = 3.14159265358979323846f;

    __shared__ float cx[32], cy[32], cz[32];
    __shared__ int   spec[32];
    __shared__ float dists[4][32], fcas[4][32], uxs[4][32], uys[4][32], uzs[4][32];
    __shared__ int   nbr[4][32];
    __shared__ int   cnt[4];
    __shared__ __align__(16) float aev[4][1284];   // rad 0..127 | ang 128..1279 | approx 1280
    __shared__ float h1[4][64], h2[4][32], h3[4][16];
    __shared__ float czl[8], szl[8];
    __shared__ float evals[4];

    if (t < 32) {
        int g = b * NA + t;
        cx[t] = coords[g*3+0]; cy[t] = coords[g*3+1]; cz[t] = coords[g*3+2];
        spec[t] = species[g] + (belong[g]-1)*4;
    }
    if (t < 8) {
        float th = PI/16.0f + (float)t * (PI/8.0f);
        czl[t] = cosf(th); szl[t] = sinf(th);
    }
    for (int idx = t; idx < 4*1284; idx += 256) ((float*)aev)[idx] = 0.0f;
    __syncthreads();

    // ---- phase 1 (threads 0..127): distances, radial, neighbor compaction ----
    if (t < 128) {
        const int li = t >> 5, j = t & 31;
        const int ia = grp*4 + li;
        float dx = cx[j]-cx[ia], dy = cy[j]-cy[ia], dz = cz[j]-cz[ia];
        float d2 = dx*dx + dy*dy + dz*dz;
        float d = sqrtf(d2 > 0.0f ? d2 : 1.0f);   // mirror reference safe-sqrt
        float inv = 1.0f / d;
        dists[li][j] = d;
        uxs[li][j] = dx*inv; uys[li][j] = dy*inv; uzs[li][j] = dz*inv;
        bool self = (j == ia);
        float fca = (!self && d <= 3.5f) ? (0.5f*cosf(PI*d/3.5f)+0.5f) : 0.0f;
        fcas[li][j] = fca;

        if (!self && d <= 5.2f) {                  // radial
            float f = 0.5f*cosf(PI*d/5.2f) + 0.5f;
            int base = spec[j]*16;
            #pragma unroll
            for (int r = 0; r < 16; ++r) {
                float dd = d - (0.9f + 0.26875f*(float)r);
                atomicAdd(&aev[li][base+r], 0.25f*expf(-16.0f*dd*dd)*f);
            }
        }
        // compact neighbors with fca>0 (deterministic, ballot-ordered)
        bool act = (fca > 0.0f);
        unsigned long long mask = __ballot(act);
        unsigned int half = (t & 32) ? (unsigned int)(mask >> 32)
                                     : (unsigned int)(mask & 0xFFFFFFFFull);
        int l31 = t & 31;
        int pos = __popc(half & ((1u << l31) - 1u));
        if (act) nbr[li][pos] = j;
        if (l31 == 0) cnt[li] = __popc(half);
    }
    __syncthreads();

    // ---- phase 2: angular over compacted unordered pairs; 64 lanes per atom ----
    {
        const int li = t >> 6, lane = t & 63;
        const int n2 = cnt[li];
        const int npairs = n2*(n2-1)/2;
        for (int p = lane; p < npairs; p += 64) {
            int m = 0, rem = p, rl = n2 - 1;
            while (rem >= rl) { rem -= rl; --rl; ++m; }
            int n = m + 1 + rem;
            int j = nbr[li][m], k = nbr[li][n];

            float wjk = fcas[li][j] * fcas[li][k];
            float cd = uxs[li][j]*uxs[li][k] + uys[li][j]*uys[li][k] + uzs[li][j]*uzs[li][k];
            cd = fminf(fmaxf(cd, -1.0f), 1.0f);
            float cth = 0.95f * cd;                 // cos(theta)
            float sth = sqrtf(1.0f - cth*cth);      // sin(theta) >= 0
            float ravg = 0.5f * (dists[li][j] + dists[li][k]);

            float f1[8];
            #pragma unroll
            for (int z = 0; z < 8; ++z) {
                float base = 0.5f*(1.0f + cth*czl[z] + sth*szl[z]);
                float x2 = base*base; x2 = x2*x2; x2 = x2*x2; x2 = x2*x2; x2 = x2*x2;
                f1[z] = x2;                          // ^32
            }
            int sj = spec[j], sk = spec[k];
            int smin = sj < sk ? sj : sk, smax = sj < sk ? sk : sj;
            int pp = 8*smin - (smin*(smin-1))/2 + (smax - smin);
            float w2 = 2.0f * wjk;
            #pragma unroll
            for (int a = 0; a < 4; ++a) {
                float da = ravg - (0.9f + 0.65f*(float)a);
                float f2 = expf(-8.0f*da*da) * w2;
                int bb = 128 + pp*32 + a*8;
                #pragma unroll
                for (int z = 0; z < 8; ++z) atomicAdd(&aev[li][bb+z], f2*f1[z]);
            }
        }
    }
    if (t < 4) aev[t][1280] = approx[b*NA + grp*4 + t];
    __syncthreads();

    // ---- layer 1: thread (w = atom, c = column), 4-way ILP accumulators ----
    {
        const int c = t & 63, w = t >> 6;
        float a0 = 0.0f, a1 = 0.0f, a2 = 0.0f, a3 = 0.0f;
        const float4* xv = (const float4*)(&aev[w][0]);
        for (int r4 = 0; r4 < 320; ++r4) {
            float4 x = xv[r4];
            int rb = r4 * 4;
            a0 = fmaf(x.x, W1[(rb+0)*64 + c], a0);
            a1 = fmaf(x.y, W1[(rb+1)*64 + c], a1);
            a2 = fmaf(x.z, W1[(rb+2)*64 + c], a2);
            a3 = fmaf(x.w, W1[(rb+3)*64 + c], a3);
        }
        float acc = b1[c] + ((a0+a2) + (a1+a3)) + aev[w][1280]*W1[1280*64 + c];
        h1[w][c] = celu01(acc);
    }
    __syncthreads();

    if (t < 128) {            // layer 2: 4 atoms x 32 cols
        int a = t >> 5, cc = t & 31;
        float s = b2[cc];
        #pragma unroll 8
        for (int r = 0; r < 64; ++r) s = fmaf(h1[a][r], W2[r*32 + cc], s);
        h2[a][cc] = celu01(s);
    }
    __syncthreads();

    if (t < 64) {             // layer 3: 4 x 16
        int a = t >> 4, cc = t & 15;
        float s = b3[cc];
        #pragma unroll
        for (int r = 0; r < 32; ++r) s = fmaf(h2[a][r], W3[r*16 + cc], s);
        h3[a][cc] = celu01(s);
    }
    __syncthreads();

    if (t < 4) {              // layer 4 per atom
        float e = b4[0];
        #pragma unroll
        for (int r = 0; r < 16; ++r) e = fmaf(h3[t][r], W4[r], e);
        evals[t] = e;
    }
    __syncthreads();

    if (t == 0) partial[blk] = (evals[0]+evals[1]) + (evals[2]+evals[3]);
}

// out[b] = sum of partial[b*8 .. b*8+7]
__global__ __launch_bounds__(64)
void reduce_kernel(const float* __restrict__ partial, float* __restrict__ out) {
    int t = threadIdx.x;
    if (t < 32) {
        const float4* p4 = (const float4*)partial;
        float4 x = p4[t*2], y = p4[t*2+1];
        out[t] = ((x.x+x.y) + (x.z+x.w)) + ((y.x+y.y) + (y.z+y.w));
    }
}

extern "C" void kernel_launch(void* const* d_in, const int* in_sizes, int n_in,
                              void* d_out, int out_size, void* d_ws, size_t ws_size,
                              hipStream_t stream) {
    (void)in_sizes; (void)n_in; (void)ws_size; (void)out_size;
    const int*   species = (const int*)d_in[0];
    const float* coords  = (const float*)d_in[1];
    const int*   belong  = (const int*)d_in[2];
    const float* approx  = (const float*)d_in[3];
    const float* W1 = (const float*)d_in[4];  const float* b1 = (const float*)d_in[5];
    const float* W2 = (const float*)d_in[6];  const float* b2 = (const float*)d_in[7];
    const float* W3 = (const float*)d_in[8];  const float* b3 = (const float*)d_in[9];
    const float* W4 = (const float*)d_in[10]; const float* b4 = (const float*)d_in[11];
    float* partial = (float*)d_ws;            // 256 floats
    float* out     = (float*)d_out;

    fused_kernel<<<NB*8, 256, 0, stream>>>(species, coords, belong, approx,
                                           W1, b1, W2, b2, W3, b3, W4, b4, partial);
    reduce_kernel<<<1, 64, 0, stream>>>(partial, out);
}

// Round 4
// 29.969 us; speedup vs baseline: 1.0062x; 1.0062x over previous
//
#include <hip/hip_runtime.h>
#include <math.h>

// ---------------------------------------------------------------------------
// ANI NNP fused: AEV (radial+angular) + 4-layer MLP per atom, block-local sum.
// B=32, A=32, NSPEC=8, AEV=1280 (+approx -> 1281)
// Kernel 1: 256 blocks x 256 threads, block = (batch, 4 atoms) -> partial[256]
// Kernel 2: 1 block, sums 8 partials per batch -> out[32]
// No memset, no global atomics, no workspace round-trip of AEV.
// ---------------------------------------------------------------------------

#define NB 32
#define NA 32

__device__ __forceinline__ float celu01(float x) {
    return x > 0.0f ? x : 0.1f * expm1f(x * 10.0f);
}

__global__ __launch_bounds__(256)
void fused_kernel(const int* __restrict__ species, const float* __restrict__ coords,
                  const int* __restrict__ belong, const float* __restrict__ approx,
                  const float* __restrict__ W1, const float* __restrict__ b1,
                  const float* __restrict__ W2, const float* __restrict__ b2,
                  const float* __restrict__ W3, const float* __restrict__ b3,
                  const float* __restrict__ W4, const float* __restrict__ b4,
                  float* __restrict__ partial) {
    const int blk = blockIdx.x;
    const int b = blk >> 3, grp = blk & 7;     // 4 atoms: ia = grp*4 + li
    const int t = threadIdx.x;
    const float PI = 3.14159265358979323846f;

    __shared__ float cx[32], cy[32], cz[32];
    __shared__ int   spec[32];
    __shared__ float dists[4][32], fcas[4][32], uxs[4][32], uys[4][32], uzs[4][32];
    __shared__ int   nbr[4][32];
    __shared__ int   cnt[4];
    __shared__ __align__(16) float aev[4][1284];   // rad 0..127 | ang 128..1279 | approx 1280
    __shared__ float h1[4][64], h2[4][32], h3[4][16];
    __shared__ float czl[8], szl[8];
    __shared__ float evals[4];

    if (t < 32) {
        int g = b * NA + t;
        cx[t] = coords[g*3+0]; cy[t] = coords[g*3+1]; cz[t] = coords[g*3+2];
        spec[t] = species[g] + (belong[g]-1)*4;
    }
    if (t < 8) {
        float th = PI/16.0f + (float)t * (PI/8.0f);
        czl[t] = cosf(th); szl[t] = sinf(th);
    }
    for (int idx = t; idx < 4*1284; idx += 256) ((float*)aev)[idx] = 0.0f;
    __syncthreads();

    // ---- phase 1 (threads 0..127): distances, radial, neighbor compaction ----
    if (t < 128) {
        const int li = t >> 5, j = t & 31;
        const int ia = grp*4 + li;
        float dx = cx[j]-cx[ia], dy = cy[j]-cy[ia], dz = cz[j]-cz[ia];
        float d2 = dx*dx + dy*dy + dz*dz;
        float d = sqrtf(d2 > 0.0f ? d2 : 1.0f);   // mirror reference safe-sqrt
        float inv = 1.0f / d;
        dists[li][j] = d;
        uxs[li][j] = dx*inv; uys[li][j] = dy*inv; uzs[li][j] = dz*inv;
        bool self = (j == ia);
        float fca = (!self && d <= 3.5f) ? (0.5f*cosf(PI*d/3.5f)+0.5f) : 0.0f;
        fcas[li][j] = fca;

        if (!self && d <= 5.2f) {                  // radial
            float f = 0.5f*cosf(PI*d/5.2f) + 0.5f;
            int base = spec[j]*16;
            #pragma unroll
            for (int r = 0; r < 16; ++r) {
                float dd = d - (0.9f + 0.26875f*(float)r);
                atomicAdd(&aev[li][base+r], 0.25f*expf(-16.0f*dd*dd)*f);
            }
        }
        // compact neighbors with fca>0 (deterministic, ballot-ordered)
        bool act = (fca > 0.0f);
        unsigned long long mask = __ballot(act);
        unsigned int half = (t & 32) ? (unsigned int)(mask >> 32)
                                     : (unsigned int)(mask & 0xFFFFFFFFull);
        int l31 = t & 31;
        int pos = __popc(half & ((1u << l31) - 1u));
        if (act) nbr[li][pos] = j;
        if (l31 == 0) cnt[li] = __popc(half);
    }
    __syncthreads();

    // ---- phase 2: angular over compacted unordered pairs; 64 lanes per atom ----
    {
        const int li = t >> 6, lane = t & 63;
        const int n2 = cnt[li];
        const int npairs = n2*(n2-1)/2;
        for (int p = lane; p < npairs; p += 64) {
            int m = 0, rem = p, rl = n2 - 1;
            while (rem >= rl) { rem -= rl; --rl; ++m; }
            int n = m + 1 + rem;
            int j = nbr[li][m], k = nbr[li][n];

            float wjk = fcas[li][j] * fcas[li][k];
            float cd = uxs[li][j]*uxs[li][k] + uys[li][j]*uys[li][k] + uzs[li][j]*uzs[li][k];
            cd = fminf(fmaxf(cd, -1.0f), 1.0f);
            float cth = 0.95f * cd;                 // cos(theta)
            float sth = sqrtf(1.0f - cth*cth);      // sin(theta) >= 0
            float ravg = 0.5f * (dists[li][j] + dists[li][k]);

            float f1[8];
            #pragma unroll
            for (int z = 0; z < 8; ++z) {
                float base = 0.5f*(1.0f + cth*czl[z] + sth*szl[z]);
                float x2 = base*base; x2 = x2*x2; x2 = x2*x2; x2 = x2*x2; x2 = x2*x2;
                f1[z] = x2;                          // ^32
            }
            int sj = spec[j], sk = spec[k];
            int smin = sj < sk ? sj : sk, smax = sj < sk ? sk : sj;
            int pp = 8*smin - (smin*(smin-1))/2 + (smax - smin);
            float w2 = 2.0f * wjk;
            #pragma unroll
            for (int a = 0; a < 4; ++a) {
                float da = ravg - (0.9f + 0.65f*(float)a);
                float f2 = expf(-8.0f*da*da) * w2;
                int bb = 128 + pp*32 + a*8;
                #pragma unroll
                for (int z = 0; z < 8; ++z) atomicAdd(&aev[li][bb+z], f2*f1[z]);
            }
        }
    }
    if (t < 4) aev[t][1280] = approx[b*NA + grp*4 + t];
    __syncthreads();

    // ---- layer 1: thread (w = atom, c = column), 4-way ILP accumulators ----
    {
        const int c = t & 63, w = t >> 6;
        float a0 = 0.0f, a1 = 0.0f, a2 = 0.0f, a3 = 0.0f;
        const float4* xv = (const float4*)(&aev[w][0]);
        for (int r4 = 0; r4 < 320; ++r4) {
            float4 x = xv[r4];
            int rb = r4 * 4;
            a0 = fmaf(x.x, W1[(rb+0)*64 + c], a0);
            a1 = fmaf(x.y, W1[(rb+1)*64 + c], a1);
            a2 = fmaf(x.z, W1[(rb+2)*64 + c], a2);
            a3 = fmaf(x.w, W1[(rb+3)*64 + c], a3);
        }
        float acc = b1[c] + ((a0+a2) + (a1+a3)) + aev[w][1280]*W1[1280*64 + c];
        h1[w][c] = celu01(acc);
    }
    __syncthreads();

    if (t < 128) {            // layer 2: 4 atoms x 32 cols
        int a = t >> 5, cc = t & 31;
        float s = b2[cc];
        #pragma unroll 8
        for (int r = 0; r < 64; ++r) s = fmaf(h1[a][r], W2[r*32 + cc], s);
        h2[a][cc] = celu01(s);
    }
    __syncthreads();

    if (t < 64) {             // layer 3: 4 x 16
        int a = t >> 4, cc = t & 15;
        float s = b3[cc];
        #pragma unroll
        for (int r = 0; r < 32; ++r) s = fmaf(h2[a][r], W3[r*16 + cc], s);
        h3[a][cc] = celu01(s);
    }
    __syncthreads();

    if (t < 4) {              // layer 4 per atom
        float e = b4[0];
        #pragma unroll
        for (int r = 0; r < 16; ++r) e = fmaf(h3[t][r], W4[r], e);
        evals[t] = e;
    }
    __syncthreads();

    if (t == 0) partial[blk] = (evals[0]+evals[1]) + (evals[2]+evals[3]);
}

// out[b] = sum of partial[b*8 .. b*8+7]
__global__ __launch_bounds__(64)
void reduce_kernel(const float* __restrict__ partial, float* __restrict__ out) {
    int t = threadIdx.x;
    if (t < 32) {
        const float4* p4 = (const float4*)partial;
        float4 x = p4[t*2], y = p4[t*2+1];
        out[t] = ((x.x+x.y) + (x.z+x.w)) + ((y.x+y.y) + (y.z+y.w));
    }
}

extern "C" void kernel_launch(void* const* d_in, const int* in_sizes, int n_in,
                              void* d_out, int out_size, void* d_ws, size_t ws_size,
                              hipStream_t stream) {
    (void)in_sizes; (void)n_in; (void)ws_size; (void)out_size;
    const int*   species = (const int*)d_in[0];
    const float* coords  = (const float*)d_in[1];
    const int*   belong  = (const int*)d_in[2];
    const float* approx  = (const float*)d_in[3];
    const float* W1 = (const float*)d_in[4];  const float* b1 = (const float*)d_in[5];
    const float* W2 = (const float*)d_in[6];  const float* b2 = (const float*)d_in[7];
    const float* W3 = (const float*)d_in[8];  const float* b3 = (const float*)d_in[9];
    const float* W4 = (const float*)d_in[10]; const float* b4 = (const float*)d_in[11];
    float* partial = (float*)d_ws;            // 256 floats
    float* out     = (float*)d_out;

    fused_kernel<<<NB*8, 256, 0, stream>>>(species, coords, belong, approx,
                                           W1, b1, W2, b2, W3, b3, W4, b4, partial);
    reduce_kernel<<<1, 64, 0, stream>>>(partial, out);
}